// Round 5
// baseline (223.844 us; speedup 1.0000x reference)
//
#include <hip/hip_runtime.h>
#include <hip/hip_bf16.h>
#include <math.h>

// GatingNetwork R11: kill the B-stream hotspot — 64 tokens/wave, Ksplit=4.
//   logits = x[16384,2048] @ W[2048,64] + b; softmax; top-2.
//   Out (fp32 flat): topk_w[T,2] | topk_idx[T,2] (float) | weights[T,E].
//
// R10 post-mortem: spills fixed (WRITE 4.4MB, VGPR 96) but 80.5us with
// MfmaUtil 12 / VALU 20 / HBM 12 — latency-bound. Cause: 4096 waves x
// 192KB = 786MB of B-fragment reads from L2 for a 768KB table (1024x
// redundant), same-line hotspot -> ~12K cyc/kstep of B-wait that 300cyc
// of VALU cover + 4-wave TLP cannot hide.
//
// R11: B-traffic scales as 786MB x TLP/Ksplit. Move to TLP=1, 64 tok/wave:
//  * block 256 thr / 4 waves, block owns 64 tokens; wave w = K-quarter w
//    (16 ksteps x 32). Grid 256. B traffic 196MB; 4x more MFMA per B-byte.
//  * per kstep: 8 x-float4 loads (next kstep, distance-1), 4 m-tiles x
//    (HW-cvt split3 + 24 MFMA) = 96 MFMA, then 12-frag B refill. ~900cyc
//    of independent issue to hide L2/L3 latency under (ILP replaces TLP).
//  * HW bf16 cvt (v_cvt_pk_bf16_f32, RNE == manual RNE bit-exact for
//    finite values): split3 17 -> ~5.5 VALU ops/value.
//  * regs ~210 (acc 64 + bb 48 + xcur/xnext 64 + addr) — no launch-bounds
//    cap, 1 wave/SIMD by grid anyway. WRITE_SIZE is the spill tripwire.
//  * epilogue fits 64KB LDS: waves 1-3 dump partials (3x[64][65]=49.9KB),
//    wave 0 reduces into own acc + bias, writes lg in-place over plane 1
//    (read-before-write per entry, one owner per entry). Association
//    (w0+w1+w2+w3)+bias identical to R10 -> logits bit-identical.
//  * softmax/top-2: proven 4-lanes-per-row pattern, now 256 thr = 64 rows.
//
// Predictions: passes (absmax exactly 9.765625e-4); main 80.5 -> 15-25us;
// VGPR 200-240, WRITE stays 4.4MB; MfmaUtil 18-30; VALUBusy 25-40; Occ ~12
// (by design). If >40us clean: naked latency -> TLP=2 via Ksplit=8 next.

#define T_TOK 16384
#define DMOD  2048
#define NEXP  64
#define NKSW  16   // ksteps per wave (512 of K per wave)

typedef __attribute__((ext_vector_type(8))) short short8;
typedef __attribute__((ext_vector_type(4))) float f32x4;

#define MFMA16 __builtin_amdgcn_mfma_f32_16x16x32_bf16

__device__ __forceinline__ unsigned short bf16_rne(float f) {
  unsigned int u = __float_as_uint(f);
  unsigned int r = (u + 0x7fffu + ((u >> 16) & 1u)) >> 16;
  return (unsigned short)r;
}
__device__ __forceinline__ float bf16_up(unsigned short h) {
  return __uint_as_float(((unsigned int)h) << 16);
}
__device__ __forceinline__ unsigned short bf16_cvt(float f) {
  __hip_bfloat16 b = __float2bfloat16(f);  // RNE; lowers to v_cvt_pk_bf16_f32
  return *reinterpret_cast<unsigned short*>(&b);
}

// RNE 3-way bf16 split (manual; used in wconv — proven path, runs once).
__device__ __forceinline__ void split3_pair(float v0, float v1, unsigned& hp,
                                            unsigned& mp, unsigned& lp) {
  const unsigned short h0 = bf16_rne(v0), h1 = bf16_rne(v1);
  const float e0 = v0 - bf16_up(h0), e1 = v1 - bf16_up(h1);
  const unsigned short m0 = bf16_rne(e0), m1 = bf16_rne(e1);
  const float g0 = e0 - bf16_up(m0), g1 = e1 - bf16_up(m1);
  const unsigned short l0 = bf16_rne(g0), l1 = bf16_rne(g1);
  hp = (unsigned)h0 | ((unsigned)h1 << 16);
  mp = (unsigned)m0 | ((unsigned)m1 << 16);
  lp = (unsigned)l0 | ((unsigned)l1 << 16);
}

// HW-cvt split3 (same RNE numerics, ~3x fewer VALU ops).
__device__ __forceinline__ void split3_pair_hw(float v0, float v1,
                                               unsigned& hp, unsigned& mp,
                                               unsigned& lp) {
  const unsigned short h0 = bf16_cvt(v0), h1 = bf16_cvt(v1);
  const float e0 = v0 - bf16_up(h0), e1 = v1 - bf16_up(h1);
  const unsigned short m0 = bf16_cvt(e0), m1 = bf16_cvt(e1);
  const float g0 = e0 - bf16_up(m0), g1 = e1 - bf16_up(m1);
  const unsigned short l0 = bf16_cvt(g0), l1 = bf16_cvt(g1);
  hp = (unsigned)h0 | ((unsigned)h1 << 16);
  mp = (unsigned)m0 | ((unsigned)m1 << 16);
  lp = (unsigned)l0 | ((unsigned)l1 << 16);
}

__global__ __launch_bounds__(256) void wconv_kernel(
    const float* __restrict__ W, unsigned short* __restrict__ wp) {
  const int tid = blockIdx.x * 256 + threadIdx.x;  // 0..16383
  const int l = tid & 63;
  const int g = tid >> 6;            // g = ks*4 + nt, 0..255
  const int q = l >> 4, c = l & 15;
  const int ks = g >> 2, nt = g & 3;
  const int k0 = ks * 32 + q * 8;
  const int n = nt * 16 + c;
  float v[8];
#pragma unroll
  for (int j = 0; j < 8; ++j) v[j] = W[(size_t)(k0 + j) * NEXP + n];
  uint4 h, m, lo;
  split3_pair(v[0], v[1], h.x, m.x, lo.x);
  split3_pair(v[2], v[3], h.y, m.y, lo.y);
  split3_pair(v[4], v[5], h.z, m.z, lo.z);
  split3_pair(v[6], v[7], h.w, m.w, lo.w);
  unsigned short* base = wp + (size_t)g * 1536 + l * 8;
  *(uint4*)(base) = h;
  *(uint4*)(base + 512) = m;
  *(uint4*)(base + 1024) = lo;
}

// One kstep: issue next x loads, 4 m-tiles of (cvt + 24 MFMA), B refill.
#define KSTEP(XC, XN, KS)                                                    \
  {                                                                          \
    const int kn_ = ((KS) + 1 < NKSW) ? (KS) + 1 : NKSW - 1;                 \
    _Pragma("unroll") for (int mt = 0; mt < 4; ++mt) {                       \
      XN[2 * mt] = *(const float4*)(xg[mt] + kn_ * 32);                      \
      XN[2 * mt + 1] = *(const float4*)(xg[mt] + kn_ * 32 + 4);              \
    }                                                                        \
    _Pragma("unroll") for (int mt = 0; mt < 4; ++mt) {                       \
      uint4 h_, m_, lo_;                                                     \
      split3_pair_hw(XC[2 * mt].x, XC[2 * mt].y, h_.x, m_.x, lo_.x);         \
      split3_pair_hw(XC[2 * mt].z, XC[2 * mt].w, h_.y, m_.y, lo_.y);         \
      split3_pair_hw(XC[2 * mt + 1].x, XC[2 * mt + 1].y, h_.z, m_.z, lo_.z); \
      split3_pair_hw(XC[2 * mt + 1].z, XC[2 * mt + 1].w, h_.w, m_.w, lo_.w); \
      const short8 ah = *(short8*)&h_;                                       \
      const short8 am = *(short8*)&m_;                                       \
      const short8 al = *(short8*)&lo_;                                      \
      _Pragma("unroll") for (int nt = 0; nt < 4; ++nt) {                     \
        const short8 bh = bb[nt * 3 + 0];                                    \
        const short8 bm = bb[nt * 3 + 1];                                    \
        const short8 bl = bb[nt * 3 + 2];                                    \
        acc[mt][nt] = MFMA16(ah, bh, acc[mt][nt], 0, 0, 0);                  \
        acc[mt][nt] = MFMA16(ah, bm, acc[mt][nt], 0, 0, 0);                  \
        acc[mt][nt] = MFMA16(am, bh, acc[mt][nt], 0, 0, 0);                  \
        acc[mt][nt] = MFMA16(am, bm, acc[mt][nt], 0, 0, 0);                  \
        acc[mt][nt] = MFMA16(ah, bl, acc[mt][nt], 0, 0, 0);                  \
        acc[mt][nt] = MFMA16(al, bh, acc[mt][nt], 0, 0, 0);                  \
      }                                                                      \
    }                                                                        \
    {                                                                        \
      const unsigned short* src_ = wl + (size_t)kn_ * 6144;                  \
      _Pragma("unroll") for (int i = 0; i < 12; ++i)                         \
          bb[i] = *(const short8*)(src_ + (size_t)i * 512);                  \
    }                                                                        \
  }

__global__ __launch_bounds__(256) void gating_kernel(
    const float* __restrict__ x, const unsigned short* __restrict__ wp,
    const float* __restrict__ bias, float* __restrict__ out) {
  // planes for waves 1..3: 3 x [64][65] = 12480 floats; + red_m/red_s[64].
  __shared__ float smem[3 * 64 * 65 + 128];  // 50432 B
  float* red_m = smem + 12480;
  float* red_s = smem + 12544;
  float* lg = smem;  // logits [64][65]; overlays wave-1 plane after reduce

  const int tid = threadIdx.x;
  const int l = tid & 63;   // lane
  const int w = tid >> 6;   // wave = K-quarter
  const int q = l >> 4, c = l & 15;
  const int t0 = blockIdx.x * 64;

  // per-m-tile x row pointers (wave w covers global k [w*512, w*512+512))
  const float* xg[4];
#pragma unroll
  for (int mt = 0; mt < 4; ++mt)
    xg[mt] = x + (size_t)(t0 + mt * 16 + c) * DMOD + w * 512 + q * 8;
  const unsigned short* wl = wp + (size_t)w * NKSW * 6144 + l * 8;

  f32x4 acc[4][4];
#pragma unroll
  for (int mt = 0; mt < 4; ++mt)
#pragma unroll
    for (int nt = 0; nt < 4; ++nt) acc[mt][nt] = (f32x4){0.f, 0.f, 0.f, 0.f};

  float4 xc[8], xn[8];  // constant-indexed only (unrolled)
  short8 bb[12];

  // prologue: kstep 0 x + B
#pragma unroll
  for (int mt = 0; mt < 4; ++mt) {
    xc[2 * mt] = *(const float4*)(xg[mt]);
    xc[2 * mt + 1] = *(const float4*)(xg[mt] + 4);
  }
#pragma unroll
  for (int i = 0; i < 12; ++i)
    bb[i] = *(const short8*)(wl + (size_t)i * 512);

  for (int blk = 0; blk < 8; ++blk) {
    KSTEP(xc, xn, blk * 2)
    KSTEP(xn, xc, blk * 2 + 1)
  }

  // ---- waves 1..3: dump partials (D: col=c -> e=nt*16+c, row=q*4+r) ----
  if (w > 0) {
    float* pp = smem + (w - 1) * 4160;
#pragma unroll
    for (int mt = 0; mt < 4; ++mt)
#pragma unroll
      for (int nt = 0; nt < 4; ++nt)
#pragma unroll
        for (int r = 0; r < 4; ++r)
          pp[(mt * 16 + q * 4 + r) * 65 + nt * 16 + c] = acc[mt][nt][r];
  }
  __syncthreads();

  // ---- wave 0: reduce (w0+w1+w2+w3)+bias -> lg, in-place over plane 1 ----
  // Each entry owned by exactly one lane; smem[o] read before lg[o] write.
  if (w == 0) {
#pragma unroll
    for (int mt = 0; mt < 4; ++mt)
#pragma unroll
      for (int nt = 0; nt < 4; ++nt) {
        const float bv = bias[nt * 16 + c];
#pragma unroll
        for (int r = 0; r < 4; ++r) {
          const int o = (mt * 16 + q * 4 + r) * 65 + nt * 16 + c;
          lg[o] = ((acc[mt][nt][r] + smem[o]) + smem[4160 + o]) +
                  smem[8320 + o] + bv;
        }
      }
  }
  __syncthreads();

  // ---- softmax stats + top-2: 4 lanes per token row, 64 rows = 256 thr ----
  {
    const int row = tid >> 2;  // 0..63
    const int s = tid & 3;     // expert slice s*16..s*16+15
    const float* lr = lg + row * 65 + s * 16;
    float mx = -INFINITY;
#pragma unroll
    for (int e = 0; e < 16; ++e) mx = fmaxf(mx, lr[e]);
    mx = fmaxf(mx, __shfl_xor(mx, 1));
    mx = fmaxf(mx, __shfl_xor(mx, 2));
    float sum = 0.f, b1 = -INFINITY, b2 = -INFINITY;
    int i1 = 0, i2 = 0;
#pragma unroll
    for (int e = 0; e < 16; ++e) {
      const float v = lr[e];
      sum += expf(v - mx);
      const int idx = s * 16 + e;
      if (v > b1) {  // strict >: ties keep lowest index (jax top_k)
        b2 = b1; i2 = i1; b1 = v; i1 = idx;
      } else if (v > b2) {
        b2 = v; i2 = idx;
      }
    }
#pragma unroll
    for (int msk = 1; msk <= 2; msk <<= 1) {
      sum += __shfl_xor(sum, msk);
      const float ob1 = __shfl_xor(b1, msk);
      const int oi1 = __shfl_xor(i1, msk);
      const float ob2 = __shfl_xor(b2, msk);
      const int oi2 = __shfl_xor(i2, msk);
      float n1, n2;
      int j1, j2;
      const bool aFirst = (b1 > ob1) || (b1 == ob1 && i1 < oi1);
      if (aFirst) {
        n1 = b1; j1 = i1;
        const bool t = (b2 > ob1) || (b2 == ob1 && i2 < oi1);
        n2 = t ? b2 : ob1; j2 = t ? i2 : oi1;
      } else {
        n1 = ob1; j1 = oi1;
        const bool t = (ob2 > b1) || (ob2 == b1 && oi2 < i1);
        n2 = t ? ob2 : b1; j2 = t ? oi2 : i1;
      }
      b1 = n1; i1 = j1; b2 = n2; i2 = j2;
    }
    if (s == 0) {
      const float inv = 1.f / sum;
      const int t = t0 + row;
      float2 wv, iv;
      wv.x = expf(b1 - mx) * inv;
      wv.y = expf(b2 - mx) * inv;
      iv.x = (float)i1;
      iv.y = (float)i2;
      *(float2*)(out + 2 * t) = wv;
      *(float2*)(out + 2 * T_TOK + 2 * t) = iv;
      red_m[row] = mx;
      red_s[row] = inv;
    }
  }
  __syncthreads();

  // ---- full softmax weights, coalesced: 256 thr x 16 entries ----
#pragma unroll
  for (int r2 = 0; r2 < 16; ++r2) {
    const int idx = r2 * 256 + tid;      // 0..4095
    const int tt = idx >> 6;
    const int e = idx & 63;
    out[4 * T_TOK + (size_t)(t0 + tt) * NEXP + e] =
        expf(lg[tt * 65 + e] - red_m[tt]) * red_s[tt];
  }
}

extern "C" void kernel_launch(void* const* d_in, const int* in_sizes, int n_in,
                              void* d_out, int out_size, void* d_ws,
                              size_t ws_size, hipStream_t stream) {
  const float* x = (const float*)d_in[0];
  const float* W = (const float*)d_in[1];
  const float* b = (const float*)d_in[2];
  float* out = (float*)d_out;
  unsigned short* wp = (unsigned short*)d_ws;  // needs 786432 B
  wconv_kernel<<<dim3(64), dim3(256), 0, stream>>>(W, wp);
  gating_kernel<<<dim3(T_TOK / 64), dim3(256), 0, stream>>>(x, wp, b, out);
}

// Round 6
// 211.851 us; speedup vs baseline: 1.0566x; 1.0566x over previous
//
#include <hip/hip_runtime.h>
#include <hip/hip_bf16.h>
#include <math.h>

// GatingNetwork R12: async global_load_lds staging + counted vmcnt.
//   logits = x[16384,2048] @ W[2048,64] + b; softmax; top-2.
//   Out (fp32 flat): topk_w[T,2] | topk_idx[T,2] (float) | weights[T,E].
//
// R11 post-mortem: R10->R11 moved B-traffic 4x down / ILP 4x up / TLP 4x
// down and duration was FLAT (80.5 -> 83.4us) with all pipes idle
// (Mfma 11, VALU 13, HBM 11). Per kstep ~12.5K cyc ~= 20 loads x 600cy:
// loads fully serialized. VGPR=96 (vs ~210 design) proves the compiler
// collapsed register prefetch AGAIN (3rd time). Register pipelines are
// unwinnable at HIP level -> use the guide's proven mechanism instead:
// global_load_lds (DMA, can't be sunk, no VGPRs) + counted s_waitcnt.
//
// R12:
//  * 512 blocks x 256 thr (4 waves). Block owns 32 tokens; wave w = K-quarter
//    (16 ksteps x 32). Per kstep/wave: 12 B + 4 x global_load_lds (16B) into
//    PRIVATE per-wave LDS dbufs -> NO main-loop barriers; pipeline enforced
//    by s_waitcnt vmcnt(16) (1 set in flight; vmcnt(0) only at last kstep).
//  * LDS 128KB: B 4w x 2 x 12KB = 96KB, x 4w x 2 x 4KB = 32KB. 1 block/CU.
//  * x staged chunk-transposed (slot = h*32 + tok; permutation applied on
//    the GLOBAL source, LDS linear - rule #21): frag ds_read_b128s are
//    2-way conflicts = free (m136). B frags linear both sides.
//  * 32 tok/block halves B L2 re-reads (393MB ~= 11us < x floor 13-21us).
//  * __launch_bounds__(256,1): no spill risk (spill VMEM would corrupt the
//    vmcnt counting - correctness tripwire = WRITE_SIZE must stay 4.4MB).
//  * Numerics: same 6-term RNE split, same K-quarter association
//    (w0+w1+w2+w3)+bias as R9-R11 -> absmax exactly 9.765625e-4 expected.
//
// Predictions: main 83 -> 18-30us; WRITE 4352KB; FETCH ~69MB; MfmaUtil
// 15-25; VALUBusy 30-45; Occ ~12 (by design). Fail => swizzle/race bug;
// flat 80us => .s missing global_load_lds_dwordx4.

#define T_TOK 16384
#define DMOD  2048
#define NEXP  64
#define NKSW  16          // ksteps per wave (512 of K per wave)
#define TOKB  32          // tokens per block

typedef __attribute__((ext_vector_type(8))) short short8;
typedef __attribute__((ext_vector_type(4))) float f32x4;

#define MFMA16 __builtin_amdgcn_mfma_f32_16x16x32_bf16

__device__ __forceinline__ unsigned short bf16_rne(float f) {
  unsigned int u = __float_as_uint(f);
  unsigned int r = (u + 0x7fffu + ((u >> 16) & 1u)) >> 16;
  return (unsigned short)r;
}
__device__ __forceinline__ float bf16_up(unsigned short h) {
  return __uint_as_float(((unsigned int)h) << 16);
}
__device__ __forceinline__ unsigned short bf16_cvt(float f) {
  __hip_bfloat16 b = __float2bfloat16(f);  // RNE (proven R11)
  return *reinterpret_cast<unsigned short*>(&b);
}

// RNE 3-way bf16 split (manual; wconv path, proven).
__device__ __forceinline__ void split3_pair(float v0, float v1, unsigned& hp,
                                            unsigned& mp, unsigned& lp) {
  const unsigned short h0 = bf16_rne(v0), h1 = bf16_rne(v1);
  const float e0 = v0 - bf16_up(h0), e1 = v1 - bf16_up(h1);
  const unsigned short m0 = bf16_rne(e0), m1 = bf16_rne(e1);
  const float g0 = e0 - bf16_up(m0), g1 = e1 - bf16_up(m1);
  const unsigned short l0 = bf16_rne(g0), l1 = bf16_rne(g1);
  hp = (unsigned)h0 | ((unsigned)h1 << 16);
  mp = (unsigned)m0 | ((unsigned)m1 << 16);
  lp = (unsigned)l0 | ((unsigned)l1 << 16);
}
// HW-cvt split3 (same RNE numerics; proven R11).
__device__ __forceinline__ void split3_pair_hw(float v0, float v1,
                                               unsigned& hp, unsigned& mp,
                                               unsigned& lp) {
  const unsigned short h0 = bf16_cvt(v0), h1 = bf16_cvt(v1);
  const float e0 = v0 - bf16_up(h0), e1 = v1 - bf16_up(h1);
  const unsigned short m0 = bf16_cvt(e0), m1 = bf16_cvt(e1);
  const float g0 = e0 - bf16_up(m0), g1 = e1 - bf16_up(m1);
  const unsigned short l0 = bf16_cvt(g0), l1 = bf16_cvt(g1);
  hp = (unsigned)h0 | ((unsigned)h1 << 16);
  mp = (unsigned)m0 | ((unsigned)m1 << 16);
  lp = (unsigned)l0 | ((unsigned)l1 << 16);
}

// 16B async global->LDS DMA. Dest gets +lane*16 in HW (wave-uniform base).
__device__ __forceinline__ void glds16(const void* g, void* l) {
  __builtin_amdgcn_global_load_lds(
      (const __attribute__((address_space(1))) unsigned int*)g,
      (__attribute__((address_space(3))) unsigned int*)l, 16, 0, 0);
}

__global__ __launch_bounds__(64) void wconv_kernel(
    const float* __restrict__ W, unsigned short* __restrict__ wp) {
  const int tid = blockIdx.x * 64 + threadIdx.x;  // 0..16383
  const int l = tid & 63;
  const int g = tid >> 6;            // g = ks*4 + nt, 0..255
  const int q = l >> 4, c = l & 15;
  const int ks = g >> 2, nt = g & 3;
  const int k0 = ks * 32 + q * 8;
  const int n = nt * 16 + c;
  float v[8];
#pragma unroll
  for (int j = 0; j < 8; ++j) v[j] = W[(size_t)(k0 + j) * NEXP + n];
  uint4 h, m, lo;
  split3_pair(v[0], v[1], h.x, m.x, lo.x);
  split3_pair(v[2], v[3], h.y, m.y, lo.y);
  split3_pair(v[4], v[5], h.z, m.z, lo.z);
  split3_pair(v[6], v[7], h.w, m.w, lo.w);
  unsigned short* base = wp + (size_t)g * 1536 + l * 8;
  *(uint4*)(base) = h;
  *(uint4*)(base + 512) = m;
  *(uint4*)(base + 1024) = lo;
}

// Issue one kstep's staging set (12 B + 4 x = 16 glds) into buffer D.
#define STAGE(D, KS)                                                  \
  do {                                                                \
    char* bd_ = bbuf + (D)*12288;                                     \
    const char* bs_ = wsrc + (size_t)(KS)*12288;                      \
    _Pragma("unroll") for (int i_ = 0; i_ < 12; ++i_)                 \
        glds16(bs_ + i_ * 1024, bd_ + i_ * 1024);                     \
    char* xd_ = xbuf + (D)*4096;                                      \
    const char* xs_ = xsrc + (size_t)(KS)*128;                        \
    _Pragma("unroll") for (int j_ = 0; j_ < 4; ++j_)                  \
        glds16(xs_ + j_ * 32, xd_ + j_ * 1024);                       \
    asm volatile("" ::: "memory"); /* pin set boundary (FIFO order) */ \
  } while (0)

// Consume buffer D: wait its 16 loads, 16 ds_read_b128, convert, 48 MFMA.
#define KSTEP(D, VM)                                                   \
  do {                                                                 \
    asm volatile("s_waitcnt vmcnt(" #VM ")" ::: "memory");             \
    const char* bd_ = bbuf + (D)*12288;                                \
    const char* xd_ = xbuf + (D)*4096;                                 \
    short8 bf[12];                                                     \
    _Pragma("unroll") for (int i_ = 0; i_ < 12; ++i_)                  \
        bf[i_] = *(const short8*)(bd_ + i_ * 1024 + l * 16);           \
    _Pragma("unroll") for (int mt_ = 0; mt_ < 2; ++mt_) {              \
      const int cb_ = (mt_ * 16 + c16) * 16;                           \
      const float4 xa = *(const float4*)(xd_ + q * 1024 + cb_);        \
      const float4 xb = *(const float4*)(xd_ + q * 1024 + 512 + cb_);  \
      uint4 h_, m_, lo_;                                               \
      split3_pair_hw(xa.x, xa.y, h_.x, m_.x, lo_.x);                   \
      split3_pair_hw(xa.z, xa.w, h_.y, m_.y, lo_.y);                   \
      split3_pair_hw(xb.x, xb.y, h_.z, m_.z, lo_.z);                   \
      split3_pair_hw(xb.z, xb.w, h_.w, m_.w, lo_.w);                   \
      const short8 ah = *(short8*)&h_;                                 \
      const short8 am = *(short8*)&m_;                                 \
      const short8 al = *(short8*)&lo_;                                \
      _Pragma("unroll") for (int nt_ = 0; nt_ < 4; ++nt_) {            \
        const short8 bh = bf[nt_ * 3 + 0];                             \
        const short8 bm = bf[nt_ * 3 + 1];                             \
        const short8 bl = bf[nt_ * 3 + 2];                             \
        acc[mt_][nt_] = MFMA16(ah, bh, acc[mt_][nt_], 0, 0, 0);        \
        acc[mt_][nt_] = MFMA16(ah, bm, acc[mt_][nt_], 0, 0, 0);        \
        acc[mt_][nt_] = MFMA16(am, bh, acc[mt_][nt_], 0, 0, 0);        \
        acc[mt_][nt_] = MFMA16(am, bm, acc[mt_][nt_], 0, 0, 0);        \
        acc[mt_][nt_] = MFMA16(ah, bl, acc[mt_][nt_], 0, 0, 0);        \
        acc[mt_][nt_] = MFMA16(al, bh, acc[mt_][nt_], 0, 0, 0);        \
      }                                                                \
    }                                                                  \
  } while (0)

__global__ __launch_bounds__(256, 1) void gating_kernel(
    const float* __restrict__ x, const unsigned short* __restrict__ wp,
    const float* __restrict__ bias, float* __restrict__ out) {
  // [0,98304): B stage, wave w buf d at w*24576 + d*12288 (12KB each)
  // [98304,131072): x stage, wave w buf d at 98304 + w*8192 + d*4096
  __shared__ __align__(16) char smem[131072];

  const int tid = threadIdx.x;
  const int l = tid & 63;   // lane
  const int w = tid >> 6;   // wave = K-quarter
  const int q = l >> 4, c16 = l & 15;
  const int t0 = blockIdx.x * TOKB;

  char* bbuf = smem + w * 24576;
  char* xbuf = smem + 98304 + w * 8192;

  // B source: frag(kglob, i) at (kglob*12+i)*1024 + l*16 bytes; kglob=w*16+KS.
  const char* wsrc = (const char*)wp + (size_t)(w * NKSW) * 12288 + l * 16;
  // x source (chunk-transposed staging): call j, lane l -> LDS slot
  // S=j*64+l = (tok=S&31, h=S>>5); chunk = x[t0+tok][kglob*32 + h*4 ..+4).
  const char* xsrc = (const char*)x +
                     ((size_t)(t0 + (l & 31)) * DMOD + w * 512) * 4 +
                     (l >> 5) * 16;

  f32x4 acc[2][4];
#pragma unroll
  for (int mt = 0; mt < 2; ++mt)
#pragma unroll
    for (int nt = 0; nt < 4; ++nt) acc[mt][nt] = (f32x4){0.f, 0.f, 0.f, 0.f};

  // prologue: two sets in flight
  STAGE(0, 0);
  STAGE(1, 1);

  for (int it = 0; it < 7; ++it) {  // ksteps 0..13
    KSTEP(0, 16);
    STAGE(0, 2 * it + 2);
    KSTEP(1, 16);
    STAGE(1, 2 * it + 3);
  }
  KSTEP(0, 16);  // kstep 14 (set 15 still in flight)
  KSTEP(1, 0);   // kstep 15 (drain)

  // ---- epilogue (R10's proven flow, widened to 32 rows) ----
  __syncthreads();  // all waves' DMA drained (vmcnt 0) + done reading stage
  float* partial = (float*)smem;        // [4][32][65] = 8320 floats
  float* red_m = partial + 8320;        // 32
  float* red_s = red_m + 32;            // 32
  float* lg = partial;                  // summed logits [32][65]

#pragma unroll
  for (int mt = 0; mt < 2; ++mt)
#pragma unroll
    for (int nt = 0; nt < 4; ++nt)
#pragma unroll
      for (int r = 0; r < 4; ++r)
        partial[w * 2080 + (mt * 16 + q * 4 + r) * 65 + nt * 16 + c16] =
            acc[mt][nt][r];
  __syncthreads();

  // sum pass: 2048 entries, 256 thr x 8; same association as R10.
#pragma unroll
  for (int r2 = 0; r2 < 8; ++r2) {
    const int idx = r2 * 256 + tid;
    const int tt = idx >> 6;
    const int e = idx & 63;
    const int o = tt * 65 + e;
    const float s = partial[o] + partial[2080 + o] + partial[4160 + o] +
                    partial[6240 + o];
    lg[o] = s + bias[e];
  }
  __syncthreads();

  // softmax stats + top-2: 4 lanes per token row, 32 rows = 128 thr.
  if (tid < 128) {
    const int row = tid >> 2;  // 0..31
    const int s = tid & 3;     // expert slice s*16..s*16+15
    const float* lr = lg + row * 65 + s * 16;
    float mx = -INFINITY;
#pragma unroll
    for (int e = 0; e < 16; ++e) mx = fmaxf(mx, lr[e]);
    mx = fmaxf(mx, __shfl_xor(mx, 1));
    mx = fmaxf(mx, __shfl_xor(mx, 2));
    float sum = 0.f, b1 = -INFINITY, b2 = -INFINITY;
    int i1 = 0, i2 = 0;
#pragma unroll
    for (int e = 0; e < 16; ++e) {
      const float v = lr[e];
      sum += expf(v - mx);
      const int idx = s * 16 + e;
      if (v > b1) {  // strict >: ties keep lowest index (jax top_k)
        b2 = b1; i2 = i1; b1 = v; i1 = idx;
      } else if (v > b2) {
        b2 = v; i2 = idx;
      }
    }
#pragma unroll
    for (int msk = 1; msk <= 2; msk <<= 1) {
      sum += __shfl_xor(sum, msk);
      const float ob1 = __shfl_xor(b1, msk);
      const int oi1 = __shfl_xor(i1, msk);
      const float ob2 = __shfl_xor(b2, msk);
      const int oi2 = __shfl_xor(i2, msk);
      float n1, n2;
      int j1, j2;
      const bool aFirst = (b1 > ob1) || (b1 == ob1 && i1 < oi1);
      if (aFirst) {
        n1 = b1; j1 = i1;
        const bool t = (b2 > ob1) || (b2 == ob1 && i2 < oi1);
        n2 = t ? b2 : ob1; j2 = t ? i2 : oi1;
      } else {
        n1 = ob1; j1 = oi1;
        const bool t = (ob2 > b1) || (ob2 == b1 && oi2 < i1);
        n2 = t ? ob2 : b1; j2 = t ? oi2 : i1;
      }
      b1 = n1; i1 = j1; b2 = n2; i2 = j2;
    }
    if (s == 0) {
      const float inv = 1.f / sum;
      const int t = t0 + row;
      float2 wv, iv;
      wv.x = expf(b1 - mx) * inv;
      wv.y = expf(b2 - mx) * inv;
      iv.x = (float)i1;
      iv.y = (float)i2;
      *(float2*)(out + 2 * t) = wv;
      *(float2*)(out + 2 * T_TOK + 2 * t) = iv;
      red_m[row] = mx;
      red_s[row] = inv;
    }
  }
  __syncthreads();

  // full softmax weights, coalesced: 2048 entries, 256 thr x 8.
#pragma unroll
  for (int r2 = 0; r2 < 8; ++r2) {
    const int idx = r2 * 256 + tid;
    const int tt = idx >> 6;
    const int e = idx & 63;
    out[4 * T_TOK + (size_t)(t0 + tt) * NEXP + e] =
        expf(lg[tt * 65 + e] - red_m[tt]) * red_s[tt];
  }
}

extern "C" void kernel_launch(void* const* d_in, const int* in_sizes, int n_in,
                              void* d_out, int out_size, void* d_ws,
                              size_t ws_size, hipStream_t stream) {
  const float* x = (const float*)d_in[0];
  const float* W = (const float*)d_in[1];
  const float* b = (const float*)d_in[2];
  float* out = (float*)d_out;
  unsigned short* wp = (unsigned short*)d_ws;  // needs 786432 B
  wconv_kernel<<<dim3(256), dim3(64), 0, stream>>>(W, wp);
  gating_kernel<<<dim3(T_TOK / TOKB), dim3(256), 0, stream>>>(x, wp, b, out);
}

// Round 7
// 209.442 us; speedup vs baseline: 1.0688x; 1.0115x over previous
//
#include <hip/hip_runtime.h>
#include <hip/hip_bf16.h>
#include <math.h>

// GatingNetwork R13: R12's DMA pipeline at 64 tokens/block, single pass.
//   logits = x[16384,2048] @ W[2048,64] + b; softmax; top-2.
//   Out (fp32 flat): topk_w[T,2] | topk_idx[T,2] (float) | weights[T,E].
//
// R12 post-mortem: DMA staging worked (passed, no spills, gating dropped
// below the 78us harness fills -> ~75us from bench arithmetic) but 3 costs
// remained: (1) 512 blocks @ 1 block/CU = TWO serial device passes;
// (2) B redundancy 393MB for a 768KB table (~860 cyc/kstep/XCD of L2);
// (3) kstep compute ~500cyc < x L3/HBM latency ~600-900 -> residual stall.
//
// R13: TOKB 32->64, grid 256 = exactly 1 block/CU, single pass (kills 1);
// B traffic halves to 196MB (halves 2); kstep compute doubles to ~1000cyc
// (96 MFMA + 4 converts) doubling pipeline coverage (fixes 3).
//  * LDS 163840B exactly (HW max; 128KB static proven in R12, AITER ships
//    160KB kernels): B 4w x 2 x 12KB = 96KB, x 4w x 2 x 8KB = 64KB.
//  * Per kstep/wave set = 12 B + 8 x global_load_lds(16B); depth-2 private
//    dbufs, NO main-loop barriers, s_waitcnt vmcnt(20) steady / 0 drain.
//  * x LDS layout [u-chunk][tok] (R12's, scaled): stage call j lane l ->
//    (u=j, tok=l); read addr q*2048 + tok*16 (+1024): 2 lanes/bank = free.
//  * acc[4][4], regs ~180 < 512 @ 1 wave/SIMD; launch_bounds(256,1).
//  * Epilogue: R11's proven 64-row flow verbatim (waves 1-3 dump, wave0
//    reduce (w0+w1+w2+w3)+bias in-place, 4-lane/row softmax/top-2).
//  * Numerics: same 6-term RNE split + association as R9-R12 ->
//    absmax exactly 9.765625e-4 expected.
//
// Predictions: gating ~25-35us (stays below fills in top-5); bench dur_us
// 211.9 -> ~165-175. No spill traffic. If >=205: XCD memory wall ->
// N-split shared-x design next.

#define T_TOK 16384
#define DMOD  2048
#define NEXP  64
#define NKSW  16          // ksteps per wave (512 of K per wave)
#define TOKB  64          // tokens per block

typedef __attribute__((ext_vector_type(8))) short short8;
typedef __attribute__((ext_vector_type(4))) float f32x4;

#define MFMA16 __builtin_amdgcn_mfma_f32_16x16x32_bf16

__device__ __forceinline__ unsigned short bf16_rne(float f) {
  unsigned int u = __float_as_uint(f);
  unsigned int r = (u + 0x7fffu + ((u >> 16) & 1u)) >> 16;
  return (unsigned short)r;
}
__device__ __forceinline__ float bf16_up(unsigned short h) {
  return __uint_as_float(((unsigned int)h) << 16);
}
__device__ __forceinline__ unsigned short bf16_cvt(float f) {
  __hip_bfloat16 b = __float2bfloat16(f);  // RNE (proven R11/R12)
  return *reinterpret_cast<unsigned short*>(&b);
}

// RNE 3-way bf16 split (manual; wconv path, proven).
__device__ __forceinline__ void split3_pair(float v0, float v1, unsigned& hp,
                                            unsigned& mp, unsigned& lp) {
  const unsigned short h0 = bf16_rne(v0), h1 = bf16_rne(v1);
  const float e0 = v0 - bf16_up(h0), e1 = v1 - bf16_up(h1);
  const unsigned short m0 = bf16_rne(e0), m1 = bf16_rne(e1);
  const float g0 = e0 - bf16_up(m0), g1 = e1 - bf16_up(m1);
  const unsigned short l0 = bf16_rne(g0), l1 = bf16_rne(g1);
  hp = (unsigned)h0 | ((unsigned)h1 << 16);
  mp = (unsigned)m0 | ((unsigned)m1 << 16);
  lp = (unsigned)l0 | ((unsigned)l1 << 16);
}
// HW-cvt split3 (same RNE numerics; proven R11/R12).
__device__ __forceinline__ void split3_pair_hw(float v0, float v1,
                                               unsigned& hp, unsigned& mp,
                                               unsigned& lp) {
  const unsigned short h0 = bf16_cvt(v0), h1 = bf16_cvt(v1);
  const float e0 = v0 - bf16_up(h0), e1 = v1 - bf16_up(h1);
  const unsigned short m0 = bf16_cvt(e0), m1 = bf16_cvt(e1);
  const float g0 = e0 - bf16_up(m0), g1 = e1 - bf16_up(m1);
  const unsigned short l0 = bf16_cvt(g0), l1 = bf16_cvt(g1);
  hp = (unsigned)h0 | ((unsigned)h1 << 16);
  mp = (unsigned)m0 | ((unsigned)m1 << 16);
  lp = (unsigned)l0 | ((unsigned)l1 << 16);
}

// 16B async global->LDS DMA. Dest gets +lane*16 in HW (wave-uniform base).
__device__ __forceinline__ void glds16(const void* g, void* l) {
  __builtin_amdgcn_global_load_lds(
      (const __attribute__((address_space(1))) unsigned int*)g,
      (__attribute__((address_space(3))) unsigned int*)l, 16, 0, 0);
}

__global__ __launch_bounds__(256) void wconv_kernel(
    const float* __restrict__ W, unsigned short* __restrict__ wp) {
  const int tid = blockIdx.x * 256 + threadIdx.x;  // 0..16383
  const int l = tid & 63;
  const int g = tid >> 6;            // g = ks*4 + nt, 0..255
  const int q = l >> 4, c = l & 15;
  const int ks = g >> 2, nt = g & 3;
  const int k0 = ks * 32 + q * 8;
  const int n = nt * 16 + c;
  float v[8];
#pragma unroll
  for (int j = 0; j < 8; ++j) v[j] = W[(size_t)(k0 + j) * NEXP + n];
  uint4 h, m, lo;
  split3_pair(v[0], v[1], h.x, m.x, lo.x);
  split3_pair(v[2], v[3], h.y, m.y, lo.y);
  split3_pair(v[4], v[5], h.z, m.z, lo.z);
  split3_pair(v[6], v[7], h.w, m.w, lo.w);
  unsigned short* base = wp + (size_t)g * 1536 + l * 8;
  *(uint4*)(base) = h;
  *(uint4*)(base + 512) = m;
  *(uint4*)(base + 1024) = lo;
}

// Issue one kstep's staging set (12 B + 8 x = 20 glds) into buffer D.
#define STAGE(D, KS)                                                   \
  do {                                                                 \
    char* bd_ = bbuf + (D)*12288;                                      \
    const char* bs_ = wsrc + (size_t)(KS)*12288;                       \
    _Pragma("unroll") for (int i_ = 0; i_ < 12; ++i_)                  \
        glds16(bs_ + i_ * 1024, bd_ + i_ * 1024);                      \
    char* xd_ = xbuf + (D)*8192;                                       \
    const char* xs_ = xsrc + (size_t)(KS)*128;                         \
    _Pragma("unroll") for (int j_ = 0; j_ < 8; ++j_)                   \
        glds16(xs_ + j_ * 16, xd_ + j_ * 1024);                        \
    asm volatile("" ::: "memory"); /* pin set boundary (FIFO order) */ \
  } while (0)

// Consume buffer D: wait its 20 loads, ds_reads, convert, 96 MFMA.
#define KSTEP(D, VM)                                                    \
  do {                                                                  \
    asm volatile("s_waitcnt vmcnt(" #VM ")" ::: "memory");              \
    const char* bd_ = bbuf + (D)*12288;                                 \
    const char* xd_ = xbuf + (D)*8192;                                  \
    short8 bf[12];                                                      \
    _Pragma("unroll") for (int i_ = 0; i_ < 12; ++i_)                   \
        bf[i_] = *(const short8*)(bd_ + i_ * 1024 + l * 16);            \
    _Pragma("unroll") for (int mt_ = 0; mt_ < 4; ++mt_) {               \
      const int tok_ = mt_ * 16 + c16;                                  \
      const float4 xa = *(const float4*)(xd_ + q * 2048 + tok_ * 16);   \
      const float4 xb =                                                 \
          *(const float4*)(xd_ + q * 2048 + 1024 + tok_ * 16);          \
      uint4 h_, m_, lo_;                                                \
      split3_pair_hw(xa.x, xa.y, h_.x, m_.x, lo_.x);                    \
      split3_pair_hw(xa.z, xa.w, h_.y, m_.y, lo_.y);                    \
      split3_pair_hw(xb.x, xb.y, h_.z, m_.z, lo_.z);                    \
      split3_pair_hw(xb.z, xb.w, h_.w, m_.w, lo_.w);                    \
      const short8 ah = *(short8*)&h_;                                  \
      const short8 am = *(short8*)&m_;                                  \
      const short8 al = *(short8*)&lo_;                                 \
      _Pragma("unroll") for (int nt_ = 0; nt_ < 4; ++nt_) {             \
        const short8 bh = bf[nt_ * 3 + 0];                              \
        const short8 bm = bf[nt_ * 3 + 1];                              \
        const short8 bl = bf[nt_ * 3 + 2];                              \
        acc[mt_][nt_] = MFMA16(ah, bh, acc[mt_][nt_], 0, 0, 0);         \
        acc[mt_][nt_] = MFMA16(ah, bm, acc[mt_][nt_], 0, 0, 0);         \
        acc[mt_][nt_] = MFMA16(am, bh, acc[mt_][nt_], 0, 0, 0);         \
        acc[mt_][nt_] = MFMA16(am, bm, acc[mt_][nt_], 0, 0, 0);         \
        acc[mt_][nt_] = MFMA16(ah, bl, acc[mt_][nt_], 0, 0, 0);         \
        acc[mt_][nt_] = MFMA16(al, bh, acc[mt_][nt_], 0, 0, 0);         \
      }                                                                 \
    }                                                                   \
  } while (0)

__global__ __launch_bounds__(256, 1) void gating_kernel(
    const float* __restrict__ x, const unsigned short* __restrict__ wp,
    const float* __restrict__ bias, float* __restrict__ out) {
  // [0,98304): B stage, wave w buf d at w*24576 + d*12288 (12KB each)
  // [98304,163840): x stage, wave w buf d at 98304 + w*16384 + d*8192
  __shared__ __align__(16) char smem[163840];

  const int tid = threadIdx.x;
  const int l = tid & 63;   // lane
  const int w = tid >> 6;   // wave = K-quarter
  const int q = l >> 4, c16 = l & 15;
  const int t0 = blockIdx.x * TOKB;

  char* bbuf = smem + w * 24576;
  char* xbuf = smem + 98304 + w * 16384;

  // B source: frag(kglob,i) at (kglob*12+i)*1024 + l*16; kglob = w*16+KS.
  const char* wsrc = (const char*)wp + (size_t)(w * NKSW) * 12288 + l * 16;
  // x source: stage call j, lane l -> LDS (u=j, tok=l); chunk =
  // x[t0+l][w*512 + KS*32 + j*4 .. +4).
  const char* xsrc =
      (const char*)x + ((size_t)(t0 + l) * DMOD + w * 512) * 4;

  f32x4 acc[4][4];
#pragma unroll
  for (int mt = 0; mt < 4; ++mt)
#pragma unroll
    for (int nt = 0; nt < 4; ++nt) acc[mt][nt] = (f32x4){0.f, 0.f, 0.f, 0.f};

  // prologue: two sets in flight
  STAGE(0, 0);
  STAGE(1, 1);

  for (int it = 0; it < 7; ++it) {  // ksteps 0..13
    KSTEP(0, 20);
    STAGE(0, 2 * it + 2);
    KSTEP(1, 20);
    STAGE(1, 2 * it + 3);
  }
  KSTEP(0, 20);  // kstep 14 (set 15 still in flight)
  KSTEP(1, 0);   // kstep 15 (drain)

  // ---- epilogue: R11's proven 64-row flow (overlaid on smem) ----
  __syncthreads();  // all waves drained + done reading stage buffers
  float* partial = (float*)smem;  // waves 1..3 planes at (w-1)*4160
  float* red_m = partial + 12480;
  float* red_s = partial + 12544;
  float* lg = partial;  // logits [64][65]; overlays wave-1 plane

  if (w > 0) {
    float* pp = partial + (w - 1) * 4160;
#pragma unroll
    for (int mt = 0; mt < 4; ++mt)
#pragma unroll
      for (int nt = 0; nt < 4; ++nt)
#pragma unroll
        for (int r = 0; r < 4; ++r)
          pp[(mt * 16 + q * 4 + r) * 65 + nt * 16 + c16] = acc[mt][nt][r];
  }
  __syncthreads();

  // wave 0: reduce (w0+w1+w2+w3)+bias -> lg, in-place over plane 1.
  if (w == 0) {
#pragma unroll
    for (int mt = 0; mt < 4; ++mt)
#pragma unroll
      for (int nt = 0; nt < 4; ++nt) {
        const float bv = bias[nt * 16 + c16];
#pragma unroll
        for (int r = 0; r < 4; ++r) {
          const int o = (mt * 16 + q * 4 + r) * 65 + nt * 16 + c16;
          lg[o] = ((acc[mt][nt][r] + partial[o]) + partial[4160 + o]) +
                  partial[8320 + o] + bv;
        }
      }
  }
  __syncthreads();

  // softmax stats + top-2: 4 lanes per token row, 64 rows = 256 thr.
  {
    const int row = tid >> 2;  // 0..63
    const int s = tid & 3;     // expert slice s*16..s*16+15
    const float* lr = lg + row * 65 + s * 16;
    float mx = -INFINITY;
#pragma unroll
    for (int e = 0; e < 16; ++e) mx = fmaxf(mx, lr[e]);
    mx = fmaxf(mx, __shfl_xor(mx, 1));
    mx = fmaxf(mx, __shfl_xor(mx, 2));
    float sum = 0.f, b1 = -INFINITY, b2 = -INFINITY;
    int i1 = 0, i2 = 0;
#pragma unroll
    for (int e = 0; e < 16; ++e) {
      const float v = lr[e];
      sum += expf(v - mx);
      const int idx = s * 16 + e;
      if (v > b1) {  // strict >: ties keep lowest index (jax top_k)
        b2 = b1; i2 = i1; b1 = v; i1 = idx;
      } else if (v > b2) {
        b2 = v; i2 = idx;
      }
    }
#pragma unroll
    for (int msk = 1; msk <= 2; msk <<= 1) {
      sum += __shfl_xor(sum, msk);
      const float ob1 = __shfl_xor(b1, msk);
      const int oi1 = __shfl_xor(i1, msk);
      const float ob2 = __shfl_xor(b2, msk);
      const int oi2 = __shfl_xor(i2, msk);
      float n1, n2;
      int j1, j2;
      const bool aFirst = (b1 > ob1) || (b1 == ob1 && i1 < oi1);
      if (aFirst) {
        n1 = b1; j1 = i1;
        const bool t = (b2 > ob1) || (b2 == ob1 && i2 < oi1);
        n2 = t ? b2 : ob1; j2 = t ? i2 : oi1;
      } else {
        n1 = ob1; j1 = oi1;
        const bool t = (ob2 > b1) || (ob2 == b1 && oi2 < i1);
        n2 = t ? ob2 : b1; j2 = t ? oi2 : i1;
      }
      b1 = n1; i1 = j1; b2 = n2; i2 = j2;
    }
    if (s == 0) {
      const float inv = 1.f / sum;
      const int t = t0 + row;
      float2 wv, iv;
      wv.x = expf(b1 - mx) * inv;
      wv.y = expf(b2 - mx) * inv;
      iv.x = (float)i1;
      iv.y = (float)i2;
      *(float2*)(out + 2 * t) = wv;
      *(float2*)(out + 2 * T_TOK + 2 * t) = iv;
      red_m[row] = mx;
      red_s[row] = inv;
    }
  }
  __syncthreads();

  // full softmax weights, coalesced: 4096 entries, 256 thr x 16.
#pragma unroll
  for (int r2 = 0; r2 < 16; ++r2) {
    const int idx = r2 * 256 + tid;
    const int tt = idx >> 6;
    const int e = idx & 63;
    out[4 * T_TOK + (size_t)(t0 + tt) * NEXP + e] =
        expf(lg[tt * 65 + e] - red_m[tt]) * red_s[tt];
  }
}

extern "C" void kernel_launch(void* const* d_in, const int* in_sizes, int n_in,
                              void* d_out, int out_size, void* d_ws,
                              size_t ws_size, hipStream_t stream) {
  const float* x = (const float*)d_in[0];
  const float* W = (const float*)d_in[1];
  const float* b = (const float*)d_in[2];
  float* out = (float*)d_out;
  unsigned short* wp = (unsigned short*)d_ws;  // needs 786432 B
  wconv_kernel<<<dim3(64), dim3(256), 0, stream>>>(W, wp);
  gating_kernel<<<dim3(T_TOK / TOKB), dim3(256), 0, stream>>>(x, wp, b, out);
}

// Round 8
// 205.603 us; speedup vs baseline: 1.0887x; 1.0187x over previous
//
#include <hip/hip_runtime.h>
#include <hip/hip_bf16.h>
#include <math.h>

// GatingNetwork R14: R13 + COALESCED x staging (the actual fix).
//   logits = x[16384,2048] @ W[2048,64] + b; softmax; top-2.
//   Out (fp32 flat): topk_w[T,2] | topk_idx[T,2] (float) | weights[T,E].
//
// R13 post-mortem: regressed to ~109us/dispatch with NOTHING busy (Mfma 8.8,
// VALU 12, HBM 8.6) -> 16K cyc/kstep of pure stall. Cause: x staging gather
// was anti-coalesced since R7 — token-per-lane, rows 8KB apart, so each x
// glds16 = 64 distinct 16B segments = 64 VMEM transactions; 512/kstep/wave,
// ~2400/kstep/CU, serialized in the DMA path and sitting on the vmcnt
// critical path. R12->R13 doubled exactly this cost (4->8 scattered calls).
//
// R14 (only the x path changes):
//  * x staged as 8 tokens x full 128B row-chunk per glds16: lane l=(p=l>>3,
//    s=l&7) reads x[t0+8j+p][kbase+((s^p)*4)..+4) -> 8 contiguous 128B
//    segments/call, 64/kstep (8x fewer transactions).
//  * s^p = guide's XOR bank-swizzle ((row&7)<<4, G4) applied on the GLOBAL
//    source (rule #21: glds LDS dest stays linear). LDS[t*128+kb*16] holds
//    k-chunk kb^(t&7); MFMA read addr = tok*128 + ((q*32+i*16)^((tok&7)<<4))
//    -> 8 distinct 16B slots, 2 lanes/bank = free (m136).
//  * Unchanged from R13: 256 blocks x 256 thr, 64 tok/block, K-split 4,
//    private per-wave LDS dbufs (B 96KB + x 64KB = 160KB), depth-2 counted
//    vmcnt(20), no main-loop barriers, 12-glds B path, R11 epilogue,
//    6-term RNE split numerics (absmax exactly 9.765625e-4 expected).
//
// Predictions: gating 109 -> 25-40us (below the 78us fills); bench dur_us
// 209 -> 150-175; WRITE stays 4352KB; FETCH 69-100MB; conflicts <500K.
// If gating still >60us with utils low: per-CU DMA/L2 path is the wall ->
// wave-shared B staging (barriered) next.

#define T_TOK 16384
#define DMOD  2048
#define NEXP  64
#define NKSW  16          // ksteps per wave (512 of K per wave)
#define TOKB  64          // tokens per block

typedef __attribute__((ext_vector_type(8))) short short8;
typedef __attribute__((ext_vector_type(4))) float f32x4;

#define MFMA16 __builtin_amdgcn_mfma_f32_16x16x32_bf16

__device__ __forceinline__ unsigned short bf16_rne(float f) {
  unsigned int u = __float_as_uint(f);
  unsigned int r = (u + 0x7fffu + ((u >> 16) & 1u)) >> 16;
  return (unsigned short)r;
}
__device__ __forceinline__ float bf16_up(unsigned short h) {
  return __uint_as_float(((unsigned int)h) << 16);
}
__device__ __forceinline__ unsigned short bf16_cvt(float f) {
  __hip_bfloat16 b = __float2bfloat16(f);  // RNE (proven R11-R13)
  return *reinterpret_cast<unsigned short*>(&b);
}

// RNE 3-way bf16 split (manual; wconv path, proven).
__device__ __forceinline__ void split3_pair(float v0, float v1, unsigned& hp,
                                            unsigned& mp, unsigned& lp) {
  const unsigned short h0 = bf16_rne(v0), h1 = bf16_rne(v1);
  const float e0 = v0 - bf16_up(h0), e1 = v1 - bf16_up(h1);
  const unsigned short m0 = bf16_rne(e0), m1 = bf16_rne(e1);
  const float g0 = e0 - bf16_up(m0), g1 = e1 - bf16_up(m1);
  const unsigned short l0 = bf16_rne(g0), l1 = bf16_rne(g1);
  hp = (unsigned)h0 | ((unsigned)h1 << 16);
  mp = (unsigned)m0 | ((unsigned)m1 << 16);
  lp = (unsigned)l0 | ((unsigned)l1 << 16);
}
// HW-cvt split3 (same RNE numerics; proven R11-R13).
__device__ __forceinline__ void split3_pair_hw(float v0, float v1,
                                               unsigned& hp, unsigned& mp,
                                               unsigned& lp) {
  const unsigned short h0 = bf16_cvt(v0), h1 = bf16_cvt(v1);
  const float e0 = v0 - bf16_up(h0), e1 = v1 - bf16_up(h1);
  const unsigned short m0 = bf16_cvt(e0), m1 = bf16_cvt(e1);
  const float g0 = e0 - bf16_up(m0), g1 = e1 - bf16_up(m1);
  const unsigned short l0 = bf16_cvt(g0), l1 = bf16_cvt(g1);
  hp = (unsigned)h0 | ((unsigned)h1 << 16);
  mp = (unsigned)m0 | ((unsigned)m1 << 16);
  lp = (unsigned)l0 | ((unsigned)l1 << 16);
}

// 16B async global->LDS DMA. Dest gets +lane*16 in HW (wave-uniform base).
__device__ __forceinline__ void glds16(const void* g, void* l) {
  __builtin_amdgcn_global_load_lds(
      (const __attribute__((address_space(1))) unsigned int*)g,
      (__attribute__((address_space(3))) unsigned int*)l, 16, 0, 0);
}

__global__ __launch_bounds__(256) void wconv_kernel(
    const float* __restrict__ W, unsigned short* __restrict__ wp) {
  const int tid = blockIdx.x * 256 + threadIdx.x;  // 0..16383
  const int l = tid & 63;
  const int g = tid >> 6;            // g = ks*4 + nt, 0..255
  const int q = l >> 4, c = l & 15;
  const int ks = g >> 2, nt = g & 3;
  const int k0 = ks * 32 + q * 8;
  const int n = nt * 16 + c;
  float v[8];
#pragma unroll
  for (int j = 0; j < 8; ++j) v[j] = W[(size_t)(k0 + j) * NEXP + n];
  uint4 h, m, lo;
  split3_pair(v[0], v[1], h.x, m.x, lo.x);
  split3_pair(v[2], v[3], h.y, m.y, lo.y);
  split3_pair(v[4], v[5], h.z, m.z, lo.z);
  split3_pair(v[6], v[7], h.w, m.w, lo.w);
  unsigned short* base = wp + (size_t)g * 1536 + l * 8;
  *(uint4*)(base) = h;
  *(uint4*)(base + 512) = m;
  *(uint4*)(base + 1024) = lo;
}

// Issue one kstep's staging set (12 B + 8 x = 20 glds) into buffer D.
// x: call j covers tokens 8j..8j+7, full 128B k-chunk each, coalesced.
#define STAGE(D, KS)                                                   \
  do {                                                                 \
    char* bd_ = bbuf + (D)*12288;                                      \
    const char* bs_ = wsrc + (size_t)(KS)*12288;                       \
    _Pragma("unroll") for (int i_ = 0; i_ < 12; ++i_)                  \
        glds16(bs_ + i_ * 1024, bd_ + i_ * 1024);                      \
    char* xd_ = xbuf + (D)*8192;                                       \
    const char* xs_ = xsrc + (size_t)(KS)*128;                         \
    _Pragma("unroll") for (int j_ = 0; j_ < 8; ++j_)                   \
        glds16(xs_ + (size_t)j_ * 8 * DMOD * 4, xd_ + j_ * 1024);      \
    asm volatile("" ::: "memory"); /* pin set boundary (FIFO order) */ \
  } while (0)

// Consume buffer D: wait its 20 loads, ds_reads (swizzled x), 96 MFMA.
#define KSTEP(D, VM)                                                    \
  do {                                                                  \
    asm volatile("s_waitcnt vmcnt(" #VM ")" ::: "memory");              \
    const char* bd_ = bbuf + (D)*12288;                                 \
    const char* xd_ = xbuf + (D)*8192;                                  \
    short8 bf[12];                                                      \
    _Pragma("unroll") for (int i_ = 0; i_ < 12; ++i_)                   \
        bf[i_] = *(const short8*)(bd_ + i_ * 1024 + l * 16);            \
    _Pragma("unroll") for (int mt_ = 0; mt_ < 4; ++mt_) {               \
      const int tok_ = mt_ * 16 + c16;                                  \
      const char* xt_ = xd_ + tok_ * 128;                               \
      const int sw_ = (tok_ & 7) << 4;                                  \
      const float4 xa = *(const float4*)(xt_ + ((q * 32) ^ sw_));       \
      const float4 xb = *(const float4*)(xt_ + ((q * 32 + 16) ^ sw_));  \
      uint4 h_, m_, lo_;                                                \
      split3_pair_hw(xa.x, xa.y, h_.x, m_.x, lo_.x);                    \
      split3_pair_hw(xa.z, xa.w, h_.y, m_.y, lo_.y);                    \
      split3_pair_hw(xb.x, xb.y, h_.z, m_.z, lo_.z);                    \
      split3_pair_hw(xb.z, xb.w, h_.w, m_.w, lo_.w);                    \
      const short8 ah = *(short8*)&h_;                                  \
      const short8 am = *(short8*)&m_;                                  \
      const short8 al = *(short8*)&lo_;                                 \
      _Pragma("unroll") for (int nt_ = 0; nt_ < 4; ++nt_) {             \
        const short8 bh = bf[nt_ * 3 + 0];                              \
        const short8 bm = bf[nt_ * 3 + 1];                              \
        const short8 bl = bf[nt_ * 3 + 2];                              \
        acc[mt_][nt_] = MFMA16(ah, bh, acc[mt_][nt_], 0, 0, 0);         \
        acc[mt_][nt_] = MFMA16(ah, bm, acc[mt_][nt_], 0, 0, 0);         \
        acc[mt_][nt_] = MFMA16(am, bh, acc[mt_][nt_], 0, 0, 0);         \
        acc[mt_][nt_] = MFMA16(am, bm, acc[mt_][nt_], 0, 0, 0);         \
        acc[mt_][nt_] = MFMA16(ah, bl, acc[mt_][nt_], 0, 0, 0);         \
        acc[mt_][nt_] = MFMA16(al, bh, acc[mt_][nt_], 0, 0, 0);         \
      }                                                                 \
    }                                                                   \
  } while (0)

__global__ __launch_bounds__(256, 1) void gating_kernel(
    const float* __restrict__ x, const unsigned short* __restrict__ wp,
    const float* __restrict__ bias, float* __restrict__ out) {
  // [0,98304): B stage, wave w buf d at w*24576 + d*12288 (12KB each)
  // [98304,163840): x stage, wave w buf d at 98304 + w*16384 + d*8192
  __shared__ __align__(16) char smem[163840];

  const int tid = threadIdx.x;
  const int l = tid & 63;   // lane
  const int w = tid >> 6;   // wave = K-quarter
  const int q = l >> 4, c16 = l & 15;
  const int t0 = blockIdx.x * TOKB;

  char* bbuf = smem + w * 24576;
  char* xbuf = smem + 98304 + w * 16384;

  // B source: frag(kglob,i) at (kglob*12+i)*1024 + l*16; kglob = w*16+KS.
  const char* wsrc = (const char*)wp + (size_t)(w * NKSW) * 12288 + l * 16;
  // x source (coalesced + inverse-swizzled): lane l = (p=l>>3, s=l&7);
  // call j reads x[t0+8j+p][w*512 + KS*32 + ((s^p)*4) .. +4).
  // LDS[t*128 + kb*16] then holds k-chunk kb^(t&7) of token t.
  const char* xsrc = (const char*)x +
                     ((size_t)(t0 + (l >> 3)) * DMOD + w * 512) * 4 +
                     (((l & 7) ^ (l >> 3)) << 4);

  f32x4 acc[4][4];
#pragma unroll
  for (int mt = 0; mt < 4; ++mt)
#pragma unroll
    for (int nt = 0; nt < 4; ++nt) acc[mt][nt] = (f32x4){0.f, 0.f, 0.f, 0.f};

  // prologue: two sets in flight
  STAGE(0, 0);
  STAGE(1, 1);

  for (int it = 0; it < 7; ++it) {  // ksteps 0..13
    KSTEP(0, 20);
    STAGE(0, 2 * it + 2);
    KSTEP(1, 20);
    STAGE(1, 2 * it + 3);
  }
  KSTEP(0, 20);  // kstep 14 (set 15 still in flight)
  KSTEP(1, 0);   // kstep 15 (drain)

  // ---- epilogue: R11's proven 64-row flow (overlaid on smem) ----
  __syncthreads();  // all waves drained + done reading stage buffers
  float* partial = (float*)smem;  // waves 1..3 planes at (w-1)*4160
  float* red_m = partial + 12480;
  float* red_s = partial + 12544;
  float* lg = partial;  // logits [64][65]; overlays wave-1 plane

  if (w > 0) {
    float* pp = partial + (w - 1) * 4160;
#pragma unroll
    for (int mt = 0; mt < 4; ++mt)
#pragma unroll
      for (int nt = 0; nt < 4; ++nt)
#pragma unroll
        for (int r = 0; r < 4; ++r)
          pp[(mt * 16 + q * 4 + r) * 65 + nt * 16 + c16] = acc[mt][nt][r];
  }
  __syncthreads();

  // wave 0: reduce (w0+w1+w2+w3)+bias -> lg, in-place over plane 1.
  if (w == 0) {
#pragma unroll
    for (int mt = 0; mt < 4; ++mt)
#pragma unroll
      for (int nt = 0; nt < 4; ++nt) {
        const float bv = bias[nt * 16 + c16];
#pragma unroll
        for (int r = 0; r < 4; ++r) {
          const int o = (mt * 16 + q * 4 + r) * 65 + nt * 16 + c16;
          lg[o] = ((acc[mt][nt][r] + partial[o]) + partial[4160 + o]) +
                  partial[8320 + o] + bv;
        }
      }
  }
  __syncthreads();

  // softmax stats + top-2: 4 lanes per token row, 64 rows = 256 thr.
  {
    const int row = tid >> 2;  // 0..63
    const int s = tid & 3;     // expert slice s*16..s*16+15
    const float* lr = lg + row * 65 + s * 16;
    float mx = -INFINITY;
#pragma unroll
    for (int e = 0; e < 16; ++e) mx = fmaxf(mx, lr[e]);
    mx = fmaxf(mx, __shfl_xor(mx, 1));
    mx = fmaxf(mx, __shfl_xor(mx, 2));
    float sum = 0.f, b1 = -INFINITY, b2 = -INFINITY;
    int i1 = 0, i2 = 0;
#pragma unroll
    for (int e = 0; e < 16; ++e) {
      const float v = lr[e];
      sum += expf(v - mx);
      const int idx = s * 16 + e;
      if (v > b1) {  // strict >: ties keep lowest index (jax top_k)
        b2 = b1; i2 = i1; b1 = v; i1 = idx;
      } else if (v > b2) {
        b2 = v; i2 = idx;
      }
    }
#pragma unroll
    for (int msk = 1; msk <= 2; msk <<= 1) {
      sum += __shfl_xor(sum, msk);
      const float ob1 = __shfl_xor(b1, msk);
      const int oi1 = __shfl_xor(i1, msk);
      const float ob2 = __shfl_xor(b2, msk);
      const int oi2 = __shfl_xor(i2, msk);
      float n1, n2;
      int j1, j2;
      const bool aFirst = (b1 > ob1) || (b1 == ob1 && i1 < oi1);
      if (aFirst) {
        n1 = b1; j1 = i1;
        const bool t = (b2 > ob1) || (b2 == ob1 && i2 < oi1);
        n2 = t ? b2 : ob1; j2 = t ? i2 : oi1;
      } else {
        n1 = ob1; j1 = oi1;
        const bool t = (ob2 > b1) || (ob2 == b1 && oi2 < i1);
        n2 = t ? ob2 : b1; j2 = t ? oi2 : i1;
      }
      b1 = n1; i1 = j1; b2 = n2; i2 = j2;
    }
    if (s == 0) {
      const float inv = 1.f / sum;
      const int t = t0 + row;
      float2 wv, iv;
      wv.x = expf(b1 - mx) * inv;
      wv.y = expf(b2 - mx) * inv;
      iv.x = (float)i1;
      iv.y = (float)i2;
      *(float2*)(out + 2 * t) = wv;
      *(float2*)(out + 2 * T_TOK + 2 * t) = iv;
      red_m[row] = mx;
      red_s[row] = inv;
    }
  }
  __syncthreads();

  // full softmax weights, coalesced: 4096 entries, 256 thr x 16.
#pragma unroll
  for (int r2 = 0; r2 < 16; ++r2) {
    const int idx = r2 * 256 + tid;
    const int tt = idx >> 6;
    const int e = idx & 63;
    out[4 * T_TOK + (size_t)(t0 + tt) * NEXP + e] =
        expf(lg[tt * 65 + e] - red_m[tt]) * red_s[tt];
  }
}

extern "C" void kernel_launch(void* const* d_in, const int* in_sizes, int n_in,
                              void* d_out, int out_size, void* d_ws,
                              size_t ws_size, hipStream_t stream) {
  const float* x = (const float*)d_in[0];
  const float* W = (const float*)d_in[1];
  const float* b = (const float*)d_in[2];
  float* out = (float*)d_out;
  unsigned short* wp = (unsigned short*)d_ws;  // needs 786432 B
  wconv_kernel<<<dim3(64), dim3(256), 0, stream>>>(W, wp);
  gating_kernel<<<dim3(T_TOK / TOKB), dim3(256), 0, stream>>>(x, wp, b, out);
}